// Round 6
// baseline (315.133 us; speedup 1.0000x reference)
//
#include <hip/hip_runtime.h>

// GCNConvSC: out = x + (D^-1/2 (A+I) D^-1/2) x W + b
// R12: R11 cache-hint experiment, compile-fixed. (R11 failed to build:
// __builtin_nontemporal_* rejects HIP_vector_type (float4/uint4); must use
// ext_vector_type. Structure otherwise identical.)
//   - THEORY: gather FETCH 190MB sits at the 8-XCD compulsory floor only
//     because the 25.6MB xh table is evicted from L3 by the ~450MB of other
//     single-use streams each iteration, and L2 windows are polluted by
//     write-allocate (agg) + csr lines during the gather itself.
//   - CHANGES vs R8: (1) nontemporal LOADS on all single-use streams (dst/ei/
//     packed/csr_src/x/agg); (2) nontemporal STORES only on full-line
//     sequential single-use outputs (gather's agg, gemm's out) -- NEVER on
//     the scattered 4B writes in scat/sort (need L2 write-combining; R6
//     k_fill lesson); (3) xh in a DENSE ws table (stride 256) so its line
//     footprint is compact; fallback to out-interleaved if ws too small.
//   - PREDICT: success = gather FETCH 190->100-150MB, dur 61->~50us.
//     null = FETCH ~190 -> gather at random-granule floor; freeze it.
// LESSON (R10): per-launch overhead is small; don't chase launch fusion.
// LESSON (R9): passes over the 1.6M edge list are the expensive CSR part;
//   keep ONE-pass scat with precomputed bases; 3 tiny scan kernels are fine.
// LESSON (R8): gather MLP exhausted at unroll-2; unroll-4 kept for free ILP.
// LESSON (R5): no fp32 atomics anywhere (slow per-lane path).
//
// Pipeline:
//  1. k_hist   per-chunk histogram over NB=782 buckets (dst>>7)
//  2. k_part/k_mid/k_applyg  exclusive scan of hist[k][blk] -> base; ptr[N]=E
//  3. k_scat   packed[pos] = src | (dst&127)<<17, bucket-grouped (int LDS fill)
//  4. k_sort   block/bucket: count+scan in LDS -> ptr, dis, dst-sorted csr_src
//  5. k_cvt    xh'[r]=bf16(dis[r]*x[r]) into dense xh table
//  6. k_gather wave/node, quarter-wave/edge, unroll-4: agg[d]=dd*(sum xh'_s + xh'_d)
//  7. k_gemm   out = x + agg @ W + b   (bf16 MFMA 16x16x32, W^T in LDS)

typedef __attribute__((ext_vector_type(8))) short short8;
typedef __attribute__((ext_vector_type(4))) float floatx4;
typedef __attribute__((ext_vector_type(4))) unsigned uintx4;

__device__ inline unsigned bf16rne(float f) {
    unsigned u = __builtin_bit_cast(unsigned, f);
    return (u + 0x7FFFu + ((u >> 16) & 1u)) >> 16;
}
__device__ inline unsigned pack2(float lo, float hi) {
    return bf16rne(lo) | (bf16rne(hi) << 16);
}
__device__ inline float bflo(unsigned u) { return __builtin_bit_cast(float, u << 16); }
__device__ inline float bfhi(unsigned u) { return __builtin_bit_cast(float, u & 0xFFFF0000u); }

#define NPB   128     // nodes per bucket (dst>>7)
#define MAXNB 1024    // LDS bound for hist/fill arrays (NB=782)
#define SRCB  17      // src bits in packed word (N=100000 < 2^17)
#define SRCMASK ((1u << SRCB) - 1u)

__global__ void k_cvt(const float* __restrict__ x, const float* __restrict__ dis,
                      char* __restrict__ xh, int xsh, int N) {
    int t = blockIdx.x * blockDim.x + threadIdx.x;
    if (t >= N * 16) return;
    int r = t >> 4, g = t & 15;
    float d = dis[r];
    const float* p = x + (size_t)r * 128 + g * 8;
    floatx4 a = __builtin_nontemporal_load((const floatx4*)p);
    floatx4 c = __builtin_nontemporal_load((const floatx4*)(p + 4));
    uintx4 v;
    v.x = pack2(d * a.x, d * a.y); v.y = pack2(d * a.z, d * a.w);
    v.z = pack2(d * c.x, d * c.y); v.w = pack2(d * c.z, d * c.w);
    // normal store: xh must stay cached for k_gather
    *(uintx4*)(xh + ((size_t)r << xsh) + g * 16) = v;
}

__global__ __launch_bounds__(256) void k_hist(const int* __restrict__ dst,
                                              int* __restrict__ hist,
                                              int E, int NB, int NBLK, int chunk) {
    __shared__ int h[MAXNB];
    int tid = threadIdx.x, b = blockIdx.x;
    for (int i = tid; i < NB; i += 256) h[i] = 0;
    __syncthreads();
    int e0 = b * chunk, e1 = min(e0 + chunk, E);
    for (int e = e0 + tid; e < e1; e += 256)
        atomicAdd(&h[__builtin_nontemporal_load(dst + e) >> 7], 1);
    __syncthreads();
    for (int k = tid; k < NB; k += 256) hist[(size_t)k * NBLK + b] = h[k];
}

// 3-kernel exclusive scan over M ints (M <= 256*1024)
__global__ __launch_bounds__(256) void k_part(const int* __restrict__ a,
                                              int* __restrict__ part, int M) {
    __shared__ int sums[256];
    int tid = threadIdx.x;
    int base = blockIdx.x * 1024 + tid * 4;
    int s = 0;
#pragma unroll
    for (int k = 0; k < 4; ++k) { int i = base + k; if (i < M) s += a[i]; }
    sums[tid] = s;
    __syncthreads();
    for (int off = 128; off > 0; off >>= 1) {
        if (tid < off) sums[tid] += sums[tid + off];
        __syncthreads();
    }
    if (tid == 0) part[blockIdx.x] = sums[0];
}

__global__ __launch_bounds__(256) void k_mid(int* __restrict__ part,
                                             int* __restrict__ ptrN,
                                             int nblk, int E) {
    __shared__ int s[256];
    int tid = threadIdx.x;
    s[tid] = (tid < nblk) ? part[tid] : 0;
    __syncthreads();
    for (int off = 1; off < 256; off <<= 1) {
        int v = (tid >= off) ? s[tid - off] : 0;
        __syncthreads();
        s[tid] += v;
        __syncthreads();
    }
    if (tid < nblk) part[tid] = tid ? s[tid - 1] : 0;
    if (tid == 0) ptrN[0] = E;
}

__global__ __launch_bounds__(256) void k_applyg(const int* __restrict__ a,
                                                const int* __restrict__ part,
                                                int* __restrict__ out, int M) {
    __shared__ int sums[256];
    int tid = threadIdx.x;
    int base = blockIdx.x * 1024 + tid * 4;
    int c[4];
    int s = 0;
#pragma unroll
    for (int k = 0; k < 4; ++k) {
        int i = base + k;
        c[k] = (i < M) ? a[i] : 0;
        s += c[k];
    }
    sums[tid] = s;
    __syncthreads();
    for (int off = 1; off < 256; off <<= 1) {
        int v = (tid >= off) ? sums[tid - off] : 0;
        __syncthreads();
        sums[tid] += v;
        __syncthreads();
    }
    int run = part[blockIdx.x] + (tid ? sums[tid - 1] : 0);
#pragma unroll
    for (int k = 0; k < 4; ++k) {
        int i = base + k;
        if (i < M) { out[i] = run; run += c[k]; }
    }
}

__global__ __launch_bounds__(256) void k_scat(const int* __restrict__ ei,
                                              const int* __restrict__ base,
                                              unsigned* __restrict__ packed,
                                              int E, int NB, int NBLK, int chunk) {
    __shared__ int fill[MAXNB];
    int tid = threadIdx.x, b = blockIdx.x;
    for (int k = tid; k < NB; k += 256) fill[k] = base[(size_t)k * NBLK + b];
    __syncthreads();
    int e0 = b * chunk, e1 = min(e0 + chunk, E);
    for (int e = e0 + tid; e < e1; e += 256) {
        int s = __builtin_nontemporal_load(ei + e);
        int d = __builtin_nontemporal_load(ei + E + e);
        int pos = atomicAdd(&fill[d >> 7], 1);
        packed[pos] = (unsigned)s | ((unsigned)(d & (NPB - 1)) << SRCB);  // normal store: write-combining
    }
}

// one block per bucket: counting-sort its segment by local dst.
__global__ __launch_bounds__(256) void k_sort(const unsigned* __restrict__ packed,
                                              const int* __restrict__ base,
                                              int* __restrict__ csr_src,
                                              int* __restrict__ ptr,
                                              float* __restrict__ dis,
                                              int E, int NB, int NBLK, int N) {
    __shared__ int cnt[NPB], scn[NPB], fill[NPB];
    int tid = threadIdx.x, k = blockIdx.x;
    int s0 = base[(size_t)k * NBLK];
    int s1 = (k + 1 < NB) ? base[(size_t)(k + 1) * NBLK] : E;
    if (tid < NPB) cnt[tid] = 0;
    __syncthreads();
    for (int j = s0 + tid; j < s1; j += 256)
        atomicAdd(&cnt[__builtin_nontemporal_load(packed + j) >> SRCB], 1);
    __syncthreads();
    if (tid < NPB) scn[tid] = cnt[tid];
    __syncthreads();
    for (int off = 1; off < NPB; off <<= 1) {
        int v = (tid < NPB && tid >= off) ? scn[tid - off] : 0;
        __syncthreads();
        if (tid < NPB) scn[tid] += v;
        __syncthreads();
    }
    if (tid < NPB) {
        int excl = scn[tid] - cnt[tid];
        fill[tid] = excl;
        int gn = k * NPB + tid;
        if (gn < N) {
            ptr[gn] = s0 + excl;
            dis[gn] = rsqrtf((float)(cnt[tid] + 1));  // +1 self loop
        }
    }
    __syncthreads();
    for (int j = s0 + tid; j < s1; j += 256) {
        unsigned p = __builtin_nontemporal_load(packed + j);
        int loc = atomicAdd(&fill[p >> SRCB], 1);
        csr_src[s0 + loc] = (int)(p & SRCMASK);  // normal store: write-combining
    }
}

// one wave per node; quarter-wave q (16 lanes x 16B) handles edges
// j = lo+q, lo+q+4, ...  Unroll-4 main, unroll-2 mid, single tail.
// Rows pre-scaled by dis[src]; self-loop weight-1; final scale by dd.
#define ACC8(v)                         \
    do {                                \
        acc[0] += bflo((v).x);          \
        acc[1] += bfhi((v).x);          \
        acc[2] += bflo((v).y);          \
        acc[3] += bfhi((v).y);          \
        acc[4] += bflo((v).z);          \
        acc[5] += bfhi((v).z);          \
        acc[6] += bflo((v).w);          \
        acc[7] += bfhi((v).w);          \
    } while (0)

__global__ __launch_bounds__(256) void k_gather(char* __restrict__ outc,
                                                const char* __restrict__ xh, int xsh,
                                                const int* __restrict__ csr_src,
                                                const int* __restrict__ ptr,
                                                const float* __restrict__ dis,
                                                int N) {
    int lane = threadIdx.x & 63;
    int q = lane >> 4, sub = lane & 15;
    int node = (blockIdx.x * blockDim.x + threadIdx.x) >> 6;
    if (node >= N) return;
    int lo = ptr[node], hi = ptr[node + 1];
    float dd = dis[node];
    const char* xb = xh + (size_t)sub * 16;  // pre-scaled bf16 rows, stride 1<<xsh

    float acc[8] = {0.f, 0.f, 0.f, 0.f, 0.f, 0.f, 0.f, 0.f};

    if (q == 0) {  // self-loop: pre-scaled row, weight 1
        uintx4 v = *(const uintx4*)(xb + ((size_t)node << xsh));
        ACC8(v);
    }
    int j = lo + q;
    for (; j + 12 < hi; j += 16) {  // 4 edges per quarter-wave in flight
        int s0 = __builtin_nontemporal_load(csr_src + j);
        int s1 = __builtin_nontemporal_load(csr_src + j + 4);
        int s2 = __builtin_nontemporal_load(csr_src + j + 8);
        int s3 = __builtin_nontemporal_load(csr_src + j + 12);
        uintx4 v0 = *(const uintx4*)(xb + ((size_t)s0 << xsh));
        uintx4 v1 = *(const uintx4*)(xb + ((size_t)s1 << xsh));
        uintx4 v2 = *(const uintx4*)(xb + ((size_t)s2 << xsh));
        uintx4 v3 = *(const uintx4*)(xb + ((size_t)s3 << xsh));
        ACC8(v0);
        ACC8(v1);
        ACC8(v2);
        ACC8(v3);
    }
    for (; j + 4 < hi; j += 8) {    // mid: 2 in flight
        int s0 = __builtin_nontemporal_load(csr_src + j);
        int s1 = __builtin_nontemporal_load(csr_src + j + 4);
        uintx4 v0 = *(const uintx4*)(xb + ((size_t)s0 << xsh));
        uintx4 v1 = *(const uintx4*)(xb + ((size_t)s1 << xsh));
        ACC8(v0);
        ACC8(v1);
    }
    if (j < hi) {
        int s = __builtin_nontemporal_load(csr_src + j);
        uintx4 v = *(const uintx4*)(xb + ((size_t)s << xsh));
        ACC8(v);
    }
#pragma unroll
    for (int i = 0; i < 8; ++i) {
        acc[i] += __shfl_xor(acc[i], 16);
        acc[i] += __shfl_xor(acc[i], 32);
    }
    if (q == 0) {
        uintx4 o;
        o.x = pack2(dd * acc[0], dd * acc[1]);
        o.y = pack2(dd * acc[2], dd * acc[3]);
        o.z = pack2(dd * acc[4], dd * acc[5]);
        o.w = pack2(dd * acc[6], dd * acc[7]);
        // nt store: full 256B line per node half, single-use until k_gemm
        __builtin_nontemporal_store(o, (uintx4*)(outc + (size_t)node * 512 + sub * 16));
    }
}

// MFMA GEMM: block = 256 thr (4 waves), 128 rows/block (wave: 2 row-tiles of 16).
// A = agg_bf16 (out rows' first halves), B = W^T bf16 in LDS.
// C/D layout: col=lane&15, row=(lane>>4)*4+reg.
__global__ __launch_bounds__(256) void k_gemm(const float* __restrict__ x,
                                              const float* __restrict__ W,
                                              const float* __restrict__ bias,
                                              float* __restrict__ out, int N) {
    __shared__ short Wt[128 * 136];
    int tid = threadIdx.x;
    for (int i = tid; i < 8192; i += 256) {
        int n = i & 127, k2 = i >> 7;
        float w0 = W[(size_t)(2 * k2) * 128 + n];
        float w1 = W[(size_t)(2 * k2 + 1) * 128 + n];
        *(unsigned*)(Wt + (size_t)n * 136 + 2 * k2) = pack2(w0, w1);
    }
    __syncthreads();

    int lane = tid & 63, wv = tid >> 6;
    int quad = lane >> 4, l16 = lane & 15;
    size_t rowb = (size_t)blockIdx.x * 128 + wv * 32;
    const char* aggc = (const char*)out;

    floatx4 acc[2][8];
#pragma unroll
    for (int rt = 0; rt < 2; ++rt)
#pragma unroll
        for (int c = 0; c < 8; ++c) acc[rt][c] = (floatx4)0.0f;

    size_t r0 = rowb + l16;      if (r0 >= (size_t)N) r0 = N - 1;
    size_t r1 = rowb + 16 + l16; if (r1 >= (size_t)N) r1 = N - 1;

    for (int ks = 0; ks < 4; ++ks) {
        int koff = (quad * 8 + ks * 32) * 2;
        short8 a0 = __builtin_nontemporal_load((const short8*)(aggc + r0 * 512 + koff));
        short8 a1 = __builtin_nontemporal_load((const short8*)(aggc + r1 * 512 + koff));
#pragma unroll
        for (int c = 0; c < 8; ++c) {
            short8 bf = *(const short8*)(Wt + (size_t)(c * 16 + l16) * 136 + quad * 8 + ks * 32);
            acc[0][c] = __builtin_amdgcn_mfma_f32_16x16x32_bf16(a0, bf, acc[0][c], 0, 0, 0);
            acc[1][c] = __builtin_amdgcn_mfma_f32_16x16x32_bf16(a1, bf, acc[1][c], 0, 0, 0);
        }
    }

#pragma unroll
    for (int rt = 0; rt < 2; ++rt) {
#pragma unroll
        for (int c = 0; c < 8; ++c) {
            float bb = bias[c * 16 + l16];
#pragma unroll
            for (int r = 0; r < 4; ++r) {
                size_t row = rowb + rt * 16 + quad * 4 + r;
                if (row < (size_t)N) {
                    size_t idx = row * 128 + c * 16 + l16;
                    float xv = __builtin_nontemporal_load(x + idx);
                    __builtin_nontemporal_store(xv + acc[rt][c][r] + bb, out + idx);
                }
            }
        }
    }
}

extern "C" void kernel_launch(void* const* d_in, const int* in_sizes, int n_in,
                              void* d_out, int out_size, void* d_ws, size_t ws_size,
                              hipStream_t stream) {
    const float* x  = (const float*)d_in[0];
    const int*   ei = (const int*)d_in[1];   // [2, E]: src row then dst row
    const float* W  = (const float*)d_in[2];
    const float* b  = (const float*)d_in[3];
    float* out = (float*)d_out;

    int N = in_sizes[0] / 128;
    int E = in_sizes[1] / 2;
    int NB = (N + NPB - 1) / NPB;            // 782 buckets

    // Chunk for CSR-build parallelism: 6144 -> ~261 blocks. Fall back to
    // 16384 if workspace can't hold the bigger hist matrix.
    int chunk = 6144;
    int NBLK, M, nscan;
    size_t base_need;
    for (;;) {
        NBLK = (E + chunk - 1) / chunk;
        M    = NB * NBLK;
        nscan = (M + 1023) / 1024;
        base_need = (size_t)4 * ((size_t)2 * E + N + (N + 1) + (size_t)2 * M + 256);
        if (base_need <= ws_size || chunk >= 16384) break;
        chunk = 16384;
    }
    // dense xh table (N x 256B) if workspace allows; else interleave in out
    bool dense = (base_need + (size_t)N * 256) <= ws_size;

    // ws: packed[E] | csr_src[E] | dis[N] | ptr[N+1] | hist[M] | base[M] | part[256] | xh[N*256]
    char* w = (char*)d_ws;
    unsigned* packed = (unsigned*)w; w += (size_t)E * 4;
    int*   csr_src = (int*)w;   w += (size_t)E * 4;
    float* dis     = (float*)w; w += (size_t)N * 4;
    int*   ptr     = (int*)w;   w += (size_t)(N + 1) * 4;
    int*   hist    = (int*)w;   w += (size_t)M * 4;
    int*   base    = (int*)w;   w += (size_t)M * 4;
    int*   part    = (int*)w;   w += (size_t)256 * 4;
    char*  xh      = dense ? w : ((char*)out + 256);
    int    xsh     = dense ? 8 : 9;

    k_hist<<<NBLK, 256, 0, stream>>>(ei + E, hist, E, NB, NBLK, chunk);
    k_part<<<nscan, 256, 0, stream>>>(hist, part, M);
    k_mid<<<1, 256, 0, stream>>>(part, ptr + N, nscan, E);
    k_applyg<<<nscan, 256, 0, stream>>>(hist, part, base, M);
    k_scat<<<NBLK, 256, 0, stream>>>(ei, base, packed, E, NB, NBLK, chunk);
    k_sort<<<NB, 256, 0, stream>>>(packed, base, csr_src, ptr, dis, E, NB, NBLK, N);
    k_cvt<<<(N * 16 + 255) / 256, 256, 0, stream>>>(x, dis, xh, xsh, N);
    k_gather<<<((size_t)N * 64 + 255) / 256, 256, 0, stream>>>((char*)out, xh, xsh, csr_src, ptr, dis, N);
    k_gemm<<<(N + 127) / 128, 256, 0, stream>>>(x, W, b, out, N);
}

// Round 7
// 282.002 us; speedup vs baseline: 1.1175x; 1.1175x over previous
//
#include <hip/hip_runtime.h>

// GCNConvSC: out = x + (D^-1/2 (A+I) D^-1/2) x W + b
// R13: revert R12's nontemporal experiment (315us, REGRESSION) to R8 spine
// (246us) + two small tweaks: chunk 12288 (longer scat write runs) and
// 256-row k_gemm blocks (half the W re-staging).
//   - LESSON (R12): __builtin_nontemporal_load poisons any sequentially-
//     walked stream: one 128B line serves ~8 iterations (broadcast csr_src
//     reads), nt bypasses L1/L2 so each iteration re-fetches the line ->
//     FETCH +84MB, gather 61->81us. nt is only safe for true once-per-line
//     access. NO nt hints anywhere.
//   - LESSON (R12): pollution theory refuted -- dense xh table + nt streams
//     did NOT cut gather FETCH. Gather FETCH 190MB == compulsory 8-XCD floor
//     (each XCD touches ~87% of the 25.6MB table; random src). Gather is
//     FROZEN at ~60.5us: MLP exhausted (R8), bytes compulsory (R12).
//   - LESSON (R10): per-launch overhead small; launch fusion not worth it.
//   - LESSON (R9): passes over the 1.6M edge list are the expensive CSR
//     part; ONE-pass scat with precomputed bases; tiny scan kernels fine.
//   - LESSON (R5): no fp32 atomics anywhere (slow per-lane path).
//   - R13a: hist/scat chunk 6144->12288: scat per-(block,bucket) write run
//     31->63B (fewer partial-line RMWs); hist 131 blocks (still ok: 6.4MB
//     read + LDS atomics).
//   - R13b: k_gemm 256 rows/block (was 128): W staging 782->391 x 64KB,
//     acc[4][8] (~190 VGPR, 2 waves/SIMD -- fine for streaming GEMM).
//
// Pipeline:
//  1. k_hist   per-chunk histogram over NB=782 buckets (dst>>7)
//  2. k_part/k_mid/k_applyg  exclusive scan of hist[k][blk] -> base; ptr[N]=E
//  3. k_scat   packed[pos] = src | (dst&127)<<17, bucket-grouped (int LDS fill)
//  4. k_sort   block/bucket: count+scan in LDS -> ptr, dis, dst-sorted csr_src
//  5. k_cvt    xh'[r]=bf16(dis[r]*x[r]) into out rows' second 256B halves
//  6. k_gather wave/node, quarter-wave/edge, unroll-4: agg[d]=dd*(sum xh'_s + xh'_d)
//  7. k_gemm   out = x + agg @ W + b   (bf16 MFMA 16x16x32, W^T in LDS)

typedef __attribute__((ext_vector_type(8))) short short8;
typedef __attribute__((ext_vector_type(4))) float floatx4;

__device__ inline unsigned bf16rne(float f) {
    unsigned u = __builtin_bit_cast(unsigned, f);
    return (u + 0x7FFFu + ((u >> 16) & 1u)) >> 16;
}
__device__ inline unsigned pack2(float lo, float hi) {
    return bf16rne(lo) | (bf16rne(hi) << 16);
}
__device__ inline float bflo(unsigned u) { return __builtin_bit_cast(float, u << 16); }
__device__ inline float bfhi(unsigned u) { return __builtin_bit_cast(float, u & 0xFFFF0000u); }

#define NPB   128     // nodes per bucket (dst>>7)
#define MAXNB 1024    // LDS bound for hist/fill arrays (NB=782)
#define SRCB  17      // src bits in packed word (N=100000 < 2^17)
#define SRCMASK ((1u << SRCB) - 1u)

__global__ void k_cvt(const float* __restrict__ x, const float* __restrict__ dis,
                      char* __restrict__ outc, int N) {
    int t = blockIdx.x * blockDim.x + threadIdx.x;
    if (t >= N * 16) return;
    int r = t >> 4, g = t & 15;
    float d = dis[r];
    const float* p = x + (size_t)r * 128 + g * 8;
    float4 a = *(const float4*)p;
    float4 c = *(const float4*)(p + 4);
    uint4 v;
    v.x = pack2(d * a.x, d * a.y); v.y = pack2(d * a.z, d * a.w);
    v.z = pack2(d * c.x, d * c.y); v.w = pack2(d * c.z, d * c.w);
    *(uint4*)(outc + (size_t)r * 512 + 256 + g * 16) = v;
}

__global__ __launch_bounds__(256) void k_hist(const int* __restrict__ dst,
                                              int* __restrict__ hist,
                                              int E, int NB, int NBLK, int chunk) {
    __shared__ int h[MAXNB];
    int tid = threadIdx.x, b = blockIdx.x;
    for (int i = tid; i < NB; i += 256) h[i] = 0;
    __syncthreads();
    int e0 = b * chunk, e1 = min(e0 + chunk, E);
    for (int e = e0 + tid; e < e1; e += 256) atomicAdd(&h[dst[e] >> 7], 1);
    __syncthreads();
    for (int k = tid; k < NB; k += 256) hist[(size_t)k * NBLK + b] = h[k];
}

// 3-kernel exclusive scan over M ints (M <= 256*1024)
__global__ __launch_bounds__(256) void k_part(const int* __restrict__ a,
                                              int* __restrict__ part, int M) {
    __shared__ int sums[256];
    int tid = threadIdx.x;
    int base = blockIdx.x * 1024 + tid * 4;
    int s = 0;
#pragma unroll
    for (int k = 0; k < 4; ++k) { int i = base + k; if (i < M) s += a[i]; }
    sums[tid] = s;
    __syncthreads();
    for (int off = 128; off > 0; off >>= 1) {
        if (tid < off) sums[tid] += sums[tid + off];
        __syncthreads();
    }
    if (tid == 0) part[blockIdx.x] = sums[0];
}

__global__ __launch_bounds__(256) void k_mid(int* __restrict__ part,
                                             int* __restrict__ ptrN,
                                             int nblk, int E) {
    __shared__ int s[256];
    int tid = threadIdx.x;
    s[tid] = (tid < nblk) ? part[tid] : 0;
    __syncthreads();
    for (int off = 1; off < 256; off <<= 1) {
        int v = (tid >= off) ? s[tid - off] : 0;
        __syncthreads();
        s[tid] += v;
        __syncthreads();
    }
    if (tid < nblk) part[tid] = tid ? s[tid - 1] : 0;
    if (tid == 0) ptrN[0] = E;
}

__global__ __launch_bounds__(256) void k_applyg(const int* __restrict__ a,
                                                const int* __restrict__ part,
                                                int* __restrict__ out, int M) {
    __shared__ int sums[256];
    int tid = threadIdx.x;
    int base = blockIdx.x * 1024 + tid * 4;
    int c[4];
    int s = 0;
#pragma unroll
    for (int k = 0; k < 4; ++k) {
        int i = base + k;
        c[k] = (i < M) ? a[i] : 0;
        s += c[k];
    }
    sums[tid] = s;
    __syncthreads();
    for (int off = 1; off < 256; off <<= 1) {
        int v = (tid >= off) ? sums[tid - off] : 0;
        __syncthreads();
        sums[tid] += v;
        __syncthreads();
    }
    int run = part[blockIdx.x] + (tid ? sums[tid - 1] : 0);
#pragma unroll
    for (int k = 0; k < 4; ++k) {
        int i = base + k;
        if (i < M) { out[i] = run; run += c[k]; }
    }
}

__global__ __launch_bounds__(256) void k_scat(const int* __restrict__ ei,
                                              const int* __restrict__ base,
                                              unsigned* __restrict__ packed,
                                              int E, int NB, int NBLK, int chunk) {
    __shared__ int fill[MAXNB];
    int tid = threadIdx.x, b = blockIdx.x;
    for (int k = tid; k < NB; k += 256) fill[k] = base[(size_t)k * NBLK + b];
    __syncthreads();
    int e0 = b * chunk, e1 = min(e0 + chunk, E);
    for (int e = e0 + tid; e < e1; e += 256) {
        int s = ei[e];
        int d = ei[E + e];
        int pos = atomicAdd(&fill[d >> 7], 1);
        packed[pos] = (unsigned)s | ((unsigned)(d & (NPB - 1)) << SRCB);
    }
}

// one block per bucket: counting-sort its segment by local dst.
// All global writes land in this block's own ~8KB segment (L2-combined).
__global__ __launch_bounds__(256) void k_sort(const unsigned* __restrict__ packed,
                                              const int* __restrict__ base,
                                              int* __restrict__ csr_src,
                                              int* __restrict__ ptr,
                                              float* __restrict__ dis,
                                              int E, int NB, int NBLK, int N) {
    __shared__ int cnt[NPB], scn[NPB], fill[NPB];
    int tid = threadIdx.x, k = blockIdx.x;
    int s0 = base[(size_t)k * NBLK];
    int s1 = (k + 1 < NB) ? base[(size_t)(k + 1) * NBLK] : E;
    if (tid < NPB) cnt[tid] = 0;
    __syncthreads();
    for (int j = s0 + tid; j < s1; j += 256) atomicAdd(&cnt[packed[j] >> SRCB], 1);
    __syncthreads();
    if (tid < NPB) scn[tid] = cnt[tid];
    __syncthreads();
    for (int off = 1; off < NPB; off <<= 1) {
        int v = (tid < NPB && tid >= off) ? scn[tid - off] : 0;
        __syncthreads();
        if (tid < NPB) scn[tid] += v;
        __syncthreads();
    }
    if (tid < NPB) {
        int excl = scn[tid] - cnt[tid];
        fill[tid] = excl;
        int gn = k * NPB + tid;
        if (gn < N) {
            ptr[gn] = s0 + excl;
            dis[gn] = rsqrtf((float)(cnt[tid] + 1));  // +1 self loop
        }
    }
    __syncthreads();
    for (int j = s0 + tid; j < s1; j += 256) {
        unsigned p = packed[j];
        int loc = atomicAdd(&fill[p >> SRCB], 1);
        csr_src[s0 + loc] = (int)(p & SRCMASK);
    }
}

// one wave per node; quarter-wave q (16 lanes x 16B = 256B bf16 row) handles
// edges j = lo+q, lo+q+4, ...  Unroll-4 main, unroll-2 mid, single tail.
// Rows pre-scaled by dis[src]; self-loop weight-1; final scale by dd.
#define ACC8(v)                         \
    do {                                \
        acc[0] += bflo((v).x);          \
        acc[1] += bfhi((v).x);          \
        acc[2] += bflo((v).y);          \
        acc[3] += bfhi((v).y);          \
        acc[4] += bflo((v).z);          \
        acc[5] += bfhi((v).z);          \
        acc[6] += bflo((v).w);          \
        acc[7] += bfhi((v).w);          \
    } while (0)

__global__ __launch_bounds__(256) void k_gather(char* __restrict__ outc,
                                                const int* __restrict__ csr_src,
                                                const int* __restrict__ ptr,
                                                const float* __restrict__ dis,
                                                int N) {
    int lane = threadIdx.x & 63;
    int q = lane >> 4, sub = lane & 15;
    int node = (blockIdx.x * blockDim.x + threadIdx.x) >> 6;
    if (node >= N) return;
    int lo = ptr[node], hi = ptr[node + 1];
    float dd = dis[node];
    const char* xb = outc + 256 + (size_t)sub * 16;  // pre-scaled bf16 row halves

    float acc[8] = {0.f, 0.f, 0.f, 0.f, 0.f, 0.f, 0.f, 0.f};

    if (q == 0) {  // self-loop: pre-scaled row, weight 1
        uint4 v = *(const uint4*)(xb + (size_t)node * 512);
        ACC8(v);
    }
    int j = lo + q;
    for (; j + 12 < hi; j += 16) {  // 4 edges per quarter-wave in flight
        int s0 = csr_src[j];
        int s1 = csr_src[j + 4];
        int s2 = csr_src[j + 8];
        int s3 = csr_src[j + 12];
        uint4 v0 = *(const uint4*)(xb + (size_t)s0 * 512);
        uint4 v1 = *(const uint4*)(xb + (size_t)s1 * 512);
        uint4 v2 = *(const uint4*)(xb + (size_t)s2 * 512);
        uint4 v3 = *(const uint4*)(xb + (size_t)s3 * 512);
        ACC8(v0);
        ACC8(v1);
        ACC8(v2);
        ACC8(v3);
    }
    for (; j + 4 < hi; j += 8) {    // mid: 2 in flight
        int s0 = csr_src[j];
        int s1 = csr_src[j + 4];
        uint4 v0 = *(const uint4*)(xb + (size_t)s0 * 512);
        uint4 v1 = *(const uint4*)(xb + (size_t)s1 * 512);
        ACC8(v0);
        ACC8(v1);
    }
    if (j < hi) {
        int s = csr_src[j];
        uint4 v = *(const uint4*)(xb + (size_t)s * 512);
        ACC8(v);
    }
#pragma unroll
    for (int i = 0; i < 8; ++i) {
        acc[i] += __shfl_xor(acc[i], 16);
        acc[i] += __shfl_xor(acc[i], 32);
    }
    if (q == 0) {
        uint4 o;
        o.x = pack2(dd * acc[0], dd * acc[1]);
        o.y = pack2(dd * acc[2], dd * acc[3]);
        o.z = pack2(dd * acc[4], dd * acc[5]);
        o.w = pack2(dd * acc[6], dd * acc[7]);
        *(uint4*)(outc + (size_t)node * 512 + sub * 16) = o;
    }
}

// MFMA GEMM: block = 256 thr (4 waves), 256 rows/block (wave: 4 row-tiles of
// 16). A = agg_bf16 (out rows' first halves), B = W^T bf16 in LDS.
// C/D layout: col=lane&15, row=(lane>>4)*4+reg.
__global__ __launch_bounds__(256) void k_gemm(const float* __restrict__ x,
                                              const float* __restrict__ W,
                                              const float* __restrict__ bias,
                                              float* __restrict__ out, int N) {
    __shared__ short Wt[128 * 136];
    int tid = threadIdx.x;
    for (int i = tid; i < 8192; i += 256) {
        int n = i & 127, k2 = i >> 7;
        float w0 = W[(size_t)(2 * k2) * 128 + n];
        float w1 = W[(size_t)(2 * k2 + 1) * 128 + n];
        *(unsigned*)(Wt + (size_t)n * 136 + 2 * k2) = pack2(w0, w1);
    }
    __syncthreads();

    int lane = tid & 63, wv = tid >> 6;
    int quad = lane >> 4, l16 = lane & 15;
    size_t rowb = (size_t)blockIdx.x * 256 + wv * 64;
    const char* aggc = (const char*)out;

    floatx4 acc[4][8];
#pragma unroll
    for (int rt = 0; rt < 4; ++rt)
#pragma unroll
        for (int c = 0; c < 8; ++c) acc[rt][c] = (floatx4)0.0f;

    size_t r[4];
#pragma unroll
    for (int rt = 0; rt < 4; ++rt) {
        r[rt] = rowb + rt * 16 + l16;
        if (r[rt] >= (size_t)N) r[rt] = N - 1;
    }

    for (int ks = 0; ks < 4; ++ks) {
        int koff = (quad * 8 + ks * 32) * 2;
        short8 a[4];
#pragma unroll
        for (int rt = 0; rt < 4; ++rt)
            a[rt] = *(const short8*)(aggc + r[rt] * 512 + koff);
#pragma unroll
        for (int c = 0; c < 8; ++c) {
            short8 bf = *(const short8*)(Wt + (size_t)(c * 16 + l16) * 136 + quad * 8 + ks * 32);
#pragma unroll
            for (int rt = 0; rt < 4; ++rt)
                acc[rt][c] = __builtin_amdgcn_mfma_f32_16x16x32_bf16(a[rt], bf, acc[rt][c], 0, 0, 0);
        }
    }

#pragma unroll
    for (int rt = 0; rt < 4; ++rt) {
#pragma unroll
        for (int c = 0; c < 8; ++c) {
            float bb = bias[c * 16 + l16];
#pragma unroll
            for (int rr = 0; rr < 4; ++rr) {
                size_t row = rowb + rt * 16 + quad * 4 + rr;
                if (row < (size_t)N) {
                    size_t idx = row * 128 + c * 16 + l16;
                    out[idx] = x[idx] + acc[rt][c][rr] + bb;
                }
            }
        }
    }
}

extern "C" void kernel_launch(void* const* d_in, const int* in_sizes, int n_in,
                              void* d_out, int out_size, void* d_ws, size_t ws_size,
                              hipStream_t stream) {
    const float* x  = (const float*)d_in[0];
    const int*   ei = (const int*)d_in[1];   // [2, E]: src row then dst row
    const float* W  = (const float*)d_in[2];
    const float* b  = (const float*)d_in[3];
    float* out = (float*)d_out;

    int N = in_sizes[0] / 128;
    int E = in_sizes[1] / 2;
    int NB = (N + NPB - 1) / NPB;            // 782 buckets

    // chunk 12288: scat write runs ~63B (was 31B at 6144); hist 131 blocks.
    // Fall back to 16384 if workspace can't hold the hist matrix.
    int chunk = 12288;
    int NBLK, M, nscan;
    size_t need;
    for (;;) {
        NBLK = (E + chunk - 1) / chunk;
        M    = NB * NBLK;
        nscan = (M + 1023) / 1024;
        need = (size_t)4 * ((size_t)2 * E + N + (N + 1) + (size_t)2 * M + 256);
        if (need <= ws_size || chunk >= 16384) break;
        chunk = 16384;
    }
    // (E=1.6M, chunk=12288 -> NBLK=131, M=102442, nscan=101 <= 256)

    // ws: packed[E] | csr_src[E] | dis[N] | ptr[N+1] | hist[M] | base[M] | part[256]
    char* w = (char*)d_ws;
    unsigned* packed = (unsigned*)w; w += (size_t)E * 4;
    int*   csr_src = (int*)w;   w += (size_t)E * 4;
    float* dis     = (float*)w; w += (size_t)N * 4;
    int*   ptr     = (int*)w;   w += (size_t)(N + 1) * 4;
    int*   hist    = (int*)w;   w += (size_t)M * 4;
    int*   base    = (int*)w;   w += (size_t)M * 4;
    int*   part    = (int*)w;

    k_hist<<<NBLK, 256, 0, stream>>>(ei + E, hist, E, NB, NBLK, chunk);
    k_part<<<nscan, 256, 0, stream>>>(hist, part, M);
    k_mid<<<1, 256, 0, stream>>>(part, ptr + N, nscan, E);
    k_applyg<<<nscan, 256, 0, stream>>>(hist, part, base, M);
    k_scat<<<NBLK, 256, 0, stream>>>(ei, base, packed, E, NB, NBLK, chunk);
    k_sort<<<NB, 256, 0, stream>>>(packed, base, csr_src, ptr, dis, E, NB, NBLK, N);
    k_cvt<<<(N * 16 + 255) / 256, 256, 0, stream>>>(x, dis, (char*)out, N);
    k_gather<<<((size_t)N * 64 + 255) / 256, 256, 0, stream>>>((char*)out, csr_src, ptr, dis, N);
    k_gemm<<<(N + 255) / 256, 256, 0, stream>>>(x, W, b, out, N);
}

// Round 8
// 245.712 us; speedup vs baseline: 1.2825x; 1.1477x over previous
//
#include <hip/hip_runtime.h>

// GCNConvSC: out = x + (D^-1/2 (A+I) D^-1/2) x W + b
// R14: EXACT RESTORE of R8 (246us, best verified). R9-R13 all regressed:
//   - R9  (+20us): 2-pass scat + global tot atomics. LESSON: edge-list passes
//     are the expensive CSR part; ONE-pass scat with precomputed bases.
//   - R10 (+5us): cvt fused into k_sort lengthened its critical path.
//     LESSON: per-launch overhead is small; fusion into a tail helps nothing.
//   - R12 (+69us): nontemporal hints. LESSON: nt-load poisons any
//     sequentially-walked stream (one 128B line serves ~8 broadcast reads);
//     pollution theory REFUTED -- gather FETCH 190MB is the compulsory
//     8-XCD floor, not eviction.
//   - R13 (+36us): chunk 12288 halved hist/scat parallelism (CU count beats
//     write-run length); gemm acc[4][8] ~190 VGPR -> 2 waves/SIMD kills the
//     TLP a streaming GEMM needs. W restaging was L2-resident (~1.5us), not
//     worth chasing.
//   - k_gather FROZEN at ~60.5us: FETCH 190MB compulsory (confirmed 5x),
//     MLP exhausted at unroll-2 (R8), 28 VGPR, VALU 48%, HBM 45% -- a
//     random-256B-granule latency/fill-port floor no code change has moved.
//   - LESSON (R5): no fp32 atomics anywhere (slow per-lane path).
//
// Pipeline:
//  1. k_hist   per-chunk (6144) histogram over NB=782 buckets (dst>>7)
//  2. k_part/k_mid/k_applyg  exclusive scan of hist[k][blk] -> base; ptr[N]=E
//  3. k_scat   packed[pos] = src | (dst&127)<<17, bucket-grouped (int LDS fill)
//  4. k_sort   block/bucket: count+scan in LDS -> ptr, dis, dst-sorted csr_src
//  5. k_cvt    xh'[r]=bf16(dis[r]*x[r]) into out rows' second 256B halves
//  6. k_gather wave/node, quarter-wave/edge, unroll-4: agg[d]=dd*(sum xh'_s + xh'_d)
//  7. k_gemm   out = x + agg @ W + b   (bf16 MFMA 16x16x32, W^T in LDS, 128 rows/blk)

typedef __attribute__((ext_vector_type(8))) short short8;
typedef __attribute__((ext_vector_type(4))) float floatx4;

__device__ inline unsigned bf16rne(float f) {
    unsigned u = __builtin_bit_cast(unsigned, f);
    return (u + 0x7FFFu + ((u >> 16) & 1u)) >> 16;
}
__device__ inline unsigned pack2(float lo, float hi) {
    return bf16rne(lo) | (bf16rne(hi) << 16);
}
__device__ inline float bflo(unsigned u) { return __builtin_bit_cast(float, u << 16); }
__device__ inline float bfhi(unsigned u) { return __builtin_bit_cast(float, u & 0xFFFF0000u); }

#define NPB   128     // nodes per bucket (dst>>7)
#define MAXNB 1024    // LDS bound for hist/fill arrays (NB=782)
#define SRCB  17      // src bits in packed word (N=100000 < 2^17)
#define SRCMASK ((1u << SRCB) - 1u)

__global__ void k_cvt(const float* __restrict__ x, const float* __restrict__ dis,
                      char* __restrict__ outc, int N) {
    int t = blockIdx.x * blockDim.x + threadIdx.x;
    if (t >= N * 16) return;
    int r = t >> 4, g = t & 15;
    float d = dis[r];
    const float* p = x + (size_t)r * 128 + g * 8;
    float4 a = *(const float4*)p;
    float4 c = *(const float4*)(p + 4);
    uint4 v;
    v.x = pack2(d * a.x, d * a.y); v.y = pack2(d * a.z, d * a.w);
    v.z = pack2(d * c.x, d * c.y); v.w = pack2(d * c.z, d * c.w);
    *(uint4*)(outc + (size_t)r * 512 + 256 + g * 16) = v;
}

__global__ __launch_bounds__(256) void k_hist(const int* __restrict__ dst,
                                              int* __restrict__ hist,
                                              int E, int NB, int NBLK, int chunk) {
    __shared__ int h[MAXNB];
    int tid = threadIdx.x, b = blockIdx.x;
    for (int i = tid; i < NB; i += 256) h[i] = 0;
    __syncthreads();
    int e0 = b * chunk, e1 = min(e0 + chunk, E);
    for (int e = e0 + tid; e < e1; e += 256) atomicAdd(&h[dst[e] >> 7], 1);
    __syncthreads();
    for (int k = tid; k < NB; k += 256) hist[(size_t)k * NBLK + b] = h[k];
}

// 3-kernel exclusive scan over M ints (M <= 256*1024)
__global__ __launch_bounds__(256) void k_part(const int* __restrict__ a,
                                              int* __restrict__ part, int M) {
    __shared__ int sums[256];
    int tid = threadIdx.x;
    int base = blockIdx.x * 1024 + tid * 4;
    int s = 0;
#pragma unroll
    for (int k = 0; k < 4; ++k) { int i = base + k; if (i < M) s += a[i]; }
    sums[tid] = s;
    __syncthreads();
    for (int off = 128; off > 0; off >>= 1) {
        if (tid < off) sums[tid] += sums[tid + off];
        __syncthreads();
    }
    if (tid == 0) part[blockIdx.x] = sums[0];
}

__global__ __launch_bounds__(256) void k_mid(int* __restrict__ part,
                                             int* __restrict__ ptrN,
                                             int nblk, int E) {
    __shared__ int s[256];
    int tid = threadIdx.x;
    s[tid] = (tid < nblk) ? part[tid] : 0;
    __syncthreads();
    for (int off = 1; off < 256; off <<= 1) {
        int v = (tid >= off) ? s[tid - off] : 0;
        __syncthreads();
        s[tid] += v;
        __syncthreads();
    }
    if (tid < nblk) part[tid] = tid ? s[tid - 1] : 0;
    if (tid == 0) ptrN[0] = E;
}

__global__ __launch_bounds__(256) void k_applyg(const int* __restrict__ a,
                                                const int* __restrict__ part,
                                                int* __restrict__ out, int M) {
    __shared__ int sums[256];
    int tid = threadIdx.x;
    int base = blockIdx.x * 1024 + tid * 4;
    int c[4];
    int s = 0;
#pragma unroll
    for (int k = 0; k < 4; ++k) {
        int i = base + k;
        c[k] = (i < M) ? a[i] : 0;
        s += c[k];
    }
    sums[tid] = s;
    __syncthreads();
    for (int off = 1; off < 256; off <<= 1) {
        int v = (tid >= off) ? sums[tid - off] : 0;
        __syncthreads();
        sums[tid] += v;
        __syncthreads();
    }
    int run = part[blockIdx.x] + (tid ? sums[tid - 1] : 0);
#pragma unroll
    for (int k = 0; k < 4; ++k) {
        int i = base + k;
        if (i < M) { out[i] = run; run += c[k]; }
    }
}

__global__ __launch_bounds__(256) void k_scat(const int* __restrict__ ei,
                                              const int* __restrict__ base,
                                              unsigned* __restrict__ packed,
                                              int E, int NB, int NBLK, int chunk) {
    __shared__ int fill[MAXNB];
    int tid = threadIdx.x, b = blockIdx.x;
    for (int k = tid; k < NB; k += 256) fill[k] = base[(size_t)k * NBLK + b];
    __syncthreads();
    int e0 = b * chunk, e1 = min(e0 + chunk, E);
    for (int e = e0 + tid; e < e1; e += 256) {
        int s = ei[e];
        int d = ei[E + e];
        int pos = atomicAdd(&fill[d >> 7], 1);
        packed[pos] = (unsigned)s | ((unsigned)(d & (NPB - 1)) << SRCB);
    }
}

// one block per bucket: counting-sort its segment by local dst.
// All global writes land in this block's own ~8KB segment (L2-combined).
__global__ __launch_bounds__(256) void k_sort(const unsigned* __restrict__ packed,
                                              const int* __restrict__ base,
                                              int* __restrict__ csr_src,
                                              int* __restrict__ ptr,
                                              float* __restrict__ dis,
                                              int E, int NB, int NBLK, int N) {
    __shared__ int cnt[NPB], scn[NPB], fill[NPB];
    int tid = threadIdx.x, k = blockIdx.x;
    int s0 = base[(size_t)k * NBLK];
    int s1 = (k + 1 < NB) ? base[(size_t)(k + 1) * NBLK] : E;
    if (tid < NPB) cnt[tid] = 0;
    __syncthreads();
    for (int j = s0 + tid; j < s1; j += 256) atomicAdd(&cnt[packed[j] >> SRCB], 1);
    __syncthreads();
    if (tid < NPB) scn[tid] = cnt[tid];
    __syncthreads();
    for (int off = 1; off < NPB; off <<= 1) {
        int v = (tid < NPB && tid >= off) ? scn[tid - off] : 0;
        __syncthreads();
        if (tid < NPB) scn[tid] += v;
        __syncthreads();
    }
    if (tid < NPB) {
        int excl = scn[tid] - cnt[tid];
        fill[tid] = excl;
        int gn = k * NPB + tid;
        if (gn < N) {
            ptr[gn] = s0 + excl;
            dis[gn] = rsqrtf((float)(cnt[tid] + 1));  // +1 self loop
        }
    }
    __syncthreads();
    for (int j = s0 + tid; j < s1; j += 256) {
        unsigned p = packed[j];
        int loc = atomicAdd(&fill[p >> SRCB], 1);
        csr_src[s0 + loc] = (int)(p & SRCMASK);
    }
}

// one wave per node; quarter-wave q (16 lanes x 16B = 256B bf16 row) handles
// edges j = lo+q, lo+q+4, ...  Unroll-4 main, unroll-2 mid, single tail.
// Rows pre-scaled by dis[src]; self-loop weight-1; final scale by dd.
#define ACC8(v)                         \
    do {                                \
        acc[0] += bflo((v).x);          \
        acc[1] += bfhi((v).x);          \
        acc[2] += bflo((v).y);          \
        acc[3] += bfhi((v).y);          \
        acc[4] += bflo((v).z);          \
        acc[5] += bfhi((v).z);          \
        acc[6] += bflo((v).w);          \
        acc[7] += bfhi((v).w);          \
    } while (0)

__global__ __launch_bounds__(256) void k_gather(char* __restrict__ outc,
                                                const int* __restrict__ csr_src,
                                                const int* __restrict__ ptr,
                                                const float* __restrict__ dis,
                                                int N) {
    int lane = threadIdx.x & 63;
    int q = lane >> 4, sub = lane & 15;
    int node = (blockIdx.x * blockDim.x + threadIdx.x) >> 6;
    if (node >= N) return;
    int lo = ptr[node], hi = ptr[node + 1];
    float dd = dis[node];
    const char* xb = outc + 256 + (size_t)sub * 16;  // pre-scaled bf16 row halves

    float acc[8] = {0.f, 0.f, 0.f, 0.f, 0.f, 0.f, 0.f, 0.f};

    if (q == 0) {  // self-loop: pre-scaled row, weight 1
        uint4 v = *(const uint4*)(xb + (size_t)node * 512);
        ACC8(v);
    }
    int j = lo + q;
    for (; j + 12 < hi; j += 16) {  // 4 edges per quarter-wave in flight
        int s0 = csr_src[j];
        int s1 = csr_src[j + 4];
        int s2 = csr_src[j + 8];
        int s3 = csr_src[j + 12];
        uint4 v0 = *(const uint4*)(xb + (size_t)s0 * 512);
        uint4 v1 = *(const uint4*)(xb + (size_t)s1 * 512);
        uint4 v2 = *(const uint4*)(xb + (size_t)s2 * 512);
        uint4 v3 = *(const uint4*)(xb + (size_t)s3 * 512);
        ACC8(v0);
        ACC8(v1);
        ACC8(v2);
        ACC8(v3);
    }
    for (; j + 4 < hi; j += 8) {    // mid: 2 in flight
        int s0 = csr_src[j];
        int s1 = csr_src[j + 4];
        uint4 v0 = *(const uint4*)(xb + (size_t)s0 * 512);
        uint4 v1 = *(const uint4*)(xb + (size_t)s1 * 512);
        ACC8(v0);
        ACC8(v1);
    }
    if (j < hi) {
        int s = csr_src[j];
        uint4 v = *(const uint4*)(xb + (size_t)s * 512);
        ACC8(v);
    }
#pragma unroll
    for (int i = 0; i < 8; ++i) {
        acc[i] += __shfl_xor(acc[i], 16);
        acc[i] += __shfl_xor(acc[i], 32);
    }
    if (q == 0) {
        uint4 o;
        o.x = pack2(dd * acc[0], dd * acc[1]);
        o.y = pack2(dd * acc[2], dd * acc[3]);
        o.z = pack2(dd * acc[4], dd * acc[5]);
        o.w = pack2(dd * acc[6], dd * acc[7]);
        *(uint4*)(outc + (size_t)node * 512 + sub * 16) = o;
    }
}

// MFMA GEMM: block = 256 thr (4 waves), 128 rows/block (wave: 2 row-tiles of 16).
// A = agg_bf16 (out rows' first halves), B = W^T bf16 in LDS.
// C/D layout: col=lane&15, row=(lane>>4)*4+reg.
__global__ __launch_bounds__(256) void k_gemm(const float* __restrict__ x,
                                              const float* __restrict__ W,
                                              const float* __restrict__ bias,
                                              float* __restrict__ out, int N) {
    __shared__ short Wt[128 * 136];
    int tid = threadIdx.x;
    for (int i = tid; i < 8192; i += 256) {
        int n = i & 127, k2 = i >> 7;
        float w0 = W[(size_t)(2 * k2) * 128 + n];
        float w1 = W[(size_t)(2 * k2 + 1) * 128 + n];
        *(unsigned*)(Wt + (size_t)n * 136 + 2 * k2) = pack2(w0, w1);
    }
    __syncthreads();

    int lane = tid & 63, wv = tid >> 6;
    int quad = lane >> 4, l16 = lane & 15;
    size_t rowb = (size_t)blockIdx.x * 128 + wv * 32;
    const char* aggc = (const char*)out;

    floatx4 acc[2][8];
#pragma unroll
    for (int rt = 0; rt < 2; ++rt)
#pragma unroll
        for (int c = 0; c < 8; ++c) acc[rt][c] = (floatx4)0.0f;

    size_t r0 = rowb + l16;      if (r0 >= (size_t)N) r0 = N - 1;
    size_t r1 = rowb + 16 + l16; if (r1 >= (size_t)N) r1 = N - 1;

    for (int ks = 0; ks < 4; ++ks) {
        int koff = (quad * 8 + ks * 32) * 2;
        short8 a0 = *(const short8*)(aggc + r0 * 512 + koff);
        short8 a1 = *(const short8*)(aggc + r1 * 512 + koff);
#pragma unroll
        for (int c = 0; c < 8; ++c) {
            short8 bf = *(const short8*)(Wt + (size_t)(c * 16 + l16) * 136 + quad * 8 + ks * 32);
            acc[0][c] = __builtin_amdgcn_mfma_f32_16x16x32_bf16(a0, bf, acc[0][c], 0, 0, 0);
            acc[1][c] = __builtin_amdgcn_mfma_f32_16x16x32_bf16(a1, bf, acc[1][c], 0, 0, 0);
        }
    }

#pragma unroll
    for (int rt = 0; rt < 2; ++rt) {
#pragma unroll
        for (int c = 0; c < 8; ++c) {
            float bb = bias[c * 16 + l16];
#pragma unroll
            for (int r = 0; r < 4; ++r) {
                size_t row = rowb + rt * 16 + quad * 4 + r;
                if (row < (size_t)N) {
                    size_t idx = row * 128 + c * 16 + l16;
                    out[idx] = x[idx] + acc[rt][c][r] + bb;
                }
            }
        }
    }
}

extern "C" void kernel_launch(void* const* d_in, const int* in_sizes, int n_in,
                              void* d_out, int out_size, void* d_ws, size_t ws_size,
                              hipStream_t stream) {
    const float* x  = (const float*)d_in[0];
    const int*   ei = (const int*)d_in[1];   // [2, E]: src row then dst row
    const float* W  = (const float*)d_in[2];
    const float* b  = (const float*)d_in[3];
    float* out = (float*)d_out;

    int N = in_sizes[0] / 128;
    int E = in_sizes[1] / 2;
    int NB = (N + NPB - 1) / NPB;            // 782 buckets

    // Chunk for CSR-build parallelism: 6144 -> ~261 blocks (best measured;
    // 12288/16384 both slower). Fall back to 16384 if workspace is tight.
    int chunk = 6144;
    int NBLK, M, nscan;
    size_t need;
    for (;;) {
        NBLK = (E + chunk - 1) / chunk;
        M    = NB * NBLK;
        nscan = (M + 1023) / 1024;
        need = (size_t)4 * ((size_t)2 * E + N + (N + 1) + (size_t)2 * M + 256);
        if (need <= ws_size || chunk >= 16384) break;
        chunk = 16384;
    }
    // (E=1.6M, chunk=6144 -> NBLK=261, M=204102, nscan=200 <= 256)

    // ws: packed[E] | csr_src[E] | dis[N] | ptr[N+1] | hist[M] | base[M] | part[256]
    char* w = (char*)d_ws;
    unsigned* packed = (unsigned*)w; w += (size_t)E * 4;
    int*   csr_src = (int*)w;   w += (size_t)E * 4;
    float* dis     = (float*)w; w += (size_t)N * 4;
    int*   ptr     = (int*)w;   w += (size_t)(N + 1) * 4;
    int*   hist    = (int*)w;   w += (size_t)M * 4;
    int*   base    = (int*)w;   w += (size_t)M * 4;
    int*   part    = (int*)w;

    k_hist<<<NBLK, 256, 0, stream>>>(ei + E, hist, E, NB, NBLK, chunk);
    k_part<<<nscan, 256, 0, stream>>>(hist, part, M);
    k_mid<<<1, 256, 0, stream>>>(part, ptr + N, nscan, E);
    k_applyg<<<nscan, 256, 0, stream>>>(hist, part, base, M);
    k_scat<<<NBLK, 256, 0, stream>>>(ei, base, packed, E, NB, NBLK, chunk);
    k_sort<<<NB, 256, 0, stream>>>(packed, base, csr_src, ptr, dis, E, NB, NBLK, N);
    k_cvt<<<(N * 16 + 255) / 256, 256, 0, stream>>>(x, dis, (char*)out, N);
    k_gather<<<((size_t)N * 64 + 255) / 256, 256, 0, stream>>>((char*)out, csr_src, ptr, dis, N);
    k_gemm<<<(N + 127) / 128, 256, 0, stream>>>(x, W, b, out, N);
}